// Round 9
// baseline (301.440 us; speedup 1.0000x reference)
//
#include <hip/hip_runtime.h>
#include <cstdint>

// IDCT (DCT-III) of 4096x4096 fp32 via even/odd decimation + int8 MFMA GEMMs.
//   y_k       = E_k + O_k          (k < N/2)
//   y_{N-1-k} = E_k - O_k
// R13: occupancy play. R9-R12 audit: NO pipe >40% (MFMA 38, LDS 38, L2 33,
// HBM 30) and every schedule/traffic change was null -> concurrency-starved:
// 2 barrier-locked blocks/CU phase-lock, drains uncovered. Fix: BK=64,
// SINGLE-buffered 32 KB LDS -> 4 blocks/CU (__launch_bounds__(256,4),
// VGPR~110<128), 4 independent barrier domains per CU. All parts proven:
// R9 2-barrier loop + 16x16x64 MFMA + epilogue; R7 BK=64 staging + swizzle
// g^((r>>1)&3) (measured 0 conflicts); R9 XCD 8x8 swizzle (FETCH halved).

#define NN 4096
#define HH 2048   // N/2 = K-dim of the split GEMMs and half-spectrum width
#define BM 128
#define BN 128
#define BK 64     // i8 elems per K-step; 64 B rows, 4 granules of 16 B
#define NT (HH / BK)   // 32 K-steps

typedef int i32x4 __attribute__((ext_vector_type(4)));
typedef int i32x2 __attribute__((ext_vector_type(2)));

// async global->LDS, 16B per lane (HW: LDS dest = wave-uniform base + lane*16)
__device__ __forceinline__ void async_copy16(void* lds_base, const void* gptr) {
    __builtin_amdgcn_global_load_lds(
        (const __attribute__((address_space(1))) unsigned int*)gptr,
        (__attribute__((address_space(3))) unsigned int*)lds_base,
        16, 0, 0);
}

__device__ __forceinline__ int pack4(int q0, int q1, int q2, int q3) {
    return (q0 & 255) | ((q1 & 255) << 8) | ((q2 & 255) << 16) | ((q3 & 255) << 24);
}

// ---- prep ---- (unchanged; verified)
__global__ __launch_bounds__(256) void prep_i8(const float* __restrict__ x,
                                               signed char* __restrict__ Ae,
                                               signed char* __restrict__ Ao,
                                               signed char* __restrict__ CEm,
                                               signed char* __restrict__ COm,
                                               float* __restrict__ se,
                                               float* __restrict__ so) {
    const int b = blockIdx.x;
    const int t = threadIdx.x;
    const float s = 3.834951969714103e-4f;   // pi / 8192

    if (b < 4096) {
        __shared__ float wmaxe[4], wmaxo[4];
        const float* xr = x + (size_t)b * NN;
        float v[16];                          // elements n = t*16 .. t*16+15
#pragma unroll
        for (int j = 0; j < 4; ++j) {
            float4 f = ((const float4*)xr)[t * 4 + j];
            v[j * 4 + 0] = f.x; v[j * 4 + 1] = f.y;
            v[j * 4 + 2] = f.z; v[j * 4 + 3] = f.w;
        }
        float emax = 1e-30f, omax = 1e-30f;
#pragma unroll
        for (int i = 0; i < 8; ++i) {
            emax = fmaxf(emax, __builtin_fabsf(v[2 * i]));
            omax = fmaxf(omax, __builtin_fabsf(v[2 * i + 1]));
        }
        // 64-lane butterfly reduce (no barrier)
#pragma unroll
        for (int m = 1; m < 64; m <<= 1) {
            emax = fmaxf(emax, __shfl_xor(emax, m));
            omax = fmaxf(omax, __shfl_xor(omax, m));
        }
        const int wv = t >> 6;
        if ((t & 63) == 0) { wmaxe[wv] = emax; wmaxo[wv] = omax; }
        __syncthreads();
        const float rmax_e = fmaxf(fmaxf(wmaxe[0], wmaxe[1]), fmaxf(wmaxe[2], wmaxe[3]));
        const float rmax_o = fmaxf(fmaxf(wmaxo[0], wmaxo[1]), fmaxf(wmaxo[2], wmaxo[3]));
        const float inv_e = 127.0f / rmax_e, inv_o = 127.0f / rmax_o;
        int qe[8], qo[8];
#pragma unroll
        for (int i = 0; i < 8; ++i) {
            qe[i] = (int)rintf(v[2 * i] * inv_e);
            qo[i] = (int)rintf(v[2 * i + 1] * inv_o);
        }
        i32x2 oe, oo;
        oe[0] = pack4(qe[0], qe[1], qe[2], qe[3]);
        oe[1] = pack4(qe[4], qe[5], qe[6], qe[7]);
        oo[0] = pack4(qo[0], qo[1], qo[2], qo[3]);
        oo[1] = pack4(qo[4], qo[5], qo[6], qo[7]);
        ((i32x2*)(Ae + (size_t)b * HH))[t] = oe;   // m = t*8 .. t*8+7
        ((i32x2*)(Ao + (size_t)b * HH))[t] = oo;
        if (t == 0) {
            se[b] = rmax_e * (1.0f / 127.0f);
            so[b] = rmax_o * (1.0f / 127.0f);
        }
    } else if (b < 6144) {
        const int k = b - 4096;
        const int twok1 = 2 * k + 1;
        int q[8];
#pragma unroll
        for (int i = 0; i < 8; ++i) {
            int m = t * 8 + i;
            int p = (2 * m * twok1) & 16383;            // angle = p * pi/8192
            float w = (m == 0) ? 1.0f : 2.0f;
            q[i] = (int)rintf(w * __cosf((float)p * s) * 63.5f);  // scale 2/127
        }
        i32x2 o;
        o[0] = pack4(q[0], q[1], q[2], q[3]);
        o[1] = pack4(q[4], q[5], q[6], q[7]);
        ((i32x2*)(CEm + (size_t)k * HH))[t] = o;
    } else {
        const int k = b - 6144;
        const int twok1 = 2 * k + 1;
        int q[8];
#pragma unroll
        for (int i = 0; i < 8; ++i) {
            int m = t * 8 + i;
            int p = ((2 * m + 1) * twok1) & 16383;
            q[i] = (int)rintf(__cosf((float)p * s) * 127.0f);     // 2*cos, scale 2/127
        }
        i32x2 o;
        o[0] = pack4(q[0], q[1], q[2], q[3]);
        o[1] = pack4(q[4], q[5], q[6], q[7]);
        ((i32x2*)(COm + (size_t)k * HH))[t] = o;
    }
}

// ---- fused split GEMM: 4 blocks/CU, BK=64, single-buffered ----
// 128x128 tile, 4 waves 2x2, each wave 4x4 grid of 16x16x64 MFMA per branch
// per K-step. LDS 32 KB. Swizzle: phys granule = g ^ ((r>>1)&3) on both the
// pre-swizzled global source and the ds_read offset (R7-verified, 0 confl).
__global__ __launch_bounds__(256, 4) void idct_gemm5(const signed char* __restrict__ Ae,
                                                     const signed char* __restrict__ Ao,
                                                     const signed char* __restrict__ CEm,
                                                     const signed char* __restrict__ COm,
                                                     const float* __restrict__ se,
                                                     const float* __restrict__ so,
                                                     float* __restrict__ C) {
    __shared__ __align__(16) signed char sAe[BM * BK];   // 8 KB
    __shared__ __align__(16) signed char sAo[BM * BK];   // 8 KB
    __shared__ __align__(16) signed char sCE[BN * BK];   // 8 KB
    __shared__ __align__(16) signed char sCO[BN * BK];   // 8 KB  (total 32 KB)

    const int tid  = threadIdx.x;
    const int wave = tid >> 6;
    const int lane = tid & 63;
    const int waveM = wave >> 1;
    const int waveN = wave & 1;

    // XCD-aware swizzle (R9): XCD q owns an 8x8 tile of the 16x32 grid.
    const int lid = blockIdx.y * gridDim.x + blockIdx.x;   // 0..511
    const int q8  = lid & 7;
    const int jj  = lid >> 3;                              // 0..63
    const int bx  = (q8 & 1) * 8 + (jj & 7);               // 0..15
    const int by  = (q8 >> 1) * 8 + (jj >> 3);             // 0..31

    const int rowBase = by * BM;        // output rows
    const int colBase = bx * BN;        // half-spectrum cols k in [0,2048)

    i32x4 accE[4][4] = {};
    i32x4 accO[4][4] = {};

    // staging (R7 geometry): chunk = 1 KB = 16 rows x 4 granules(16B);
    // 8 chunks per matrix, 2 per wave per matrix -> 8 async issues/thread
    const int srow  = lane >> 2;              // row within chunk, 0..15
    const int sgran = lane & 3;               // physical granule this lane fills
    const int ggcol = (sgran ^ ((srow >> 1) & 3)) * 16;  // swizzle in global col
    const int quad  = lane >> 4;              // logical granule for MFMA reads
    const int poff  = (quad ^ ((lane >> 1) & 3)) * 16;   // swizzled read offset
    const int ck0   = wave * 2;               // first chunk owned by this wave

    const size_t aRow = (size_t)(rowBase + ck0 * 16 + srow) * HH + ggcol;
    const size_t bRow = (size_t)(colBase + ck0 * 16 + srow) * HH + ggcol;

#pragma unroll 1
    for (int t = 0; t < NT; ++t) {
        const size_t k0 = (size_t)t * BK;
#pragma unroll
        for (int j = 0; j < 2; ++j) {
            size_t aoff = aRow + (size_t)j * 16 * HH + k0;
            size_t boff = bRow + (size_t)j * 16 * HH + k0;
            async_copy16(&sAe[(ck0 + j) * 1024], Ae + aoff);
            async_copy16(&sAo[(ck0 + j) * 1024], Ao + aoff);
            async_copy16(&sCE[(ck0 + j) * 1024], CEm + boff);
            async_copy16(&sCO[(ck0 + j) * 1024], COm + boff);
        }
        __syncthreads();   // drains this block's staging; other 3 blocks cover

        {
            i32x4 af[4], bfr[4];
#pragma unroll
            for (int mi = 0; mi < 4; ++mi) {
                int r = waveM * 64 + mi * 16 + (lane & 15);
                af[mi] = *(const i32x4*)&sAe[r * BK + poff];
            }
#pragma unroll
            for (int ni = 0; ni < 4; ++ni) {
                int r = waveN * 64 + ni * 16 + (lane & 15);
                bfr[ni] = *(const i32x4*)&sCE[r * BK + poff];
            }
#pragma unroll
            for (int mi = 0; mi < 4; ++mi)
#pragma unroll
                for (int ni = 0; ni < 4; ++ni)
                    accE[mi][ni] = __builtin_amdgcn_mfma_i32_16x16x64_i8(
                        af[mi], bfr[ni], accE[mi][ni], 0, 0, 0);
        }
        {
            i32x4 af[4], bfr[4];
#pragma unroll
            for (int mi = 0; mi < 4; ++mi) {
                int r = waveM * 64 + mi * 16 + (lane & 15);
                af[mi] = *(const i32x4*)&sAo[r * BK + poff];
            }
#pragma unroll
            for (int ni = 0; ni < 4; ++ni) {
                int r = waveN * 64 + ni * 16 + (lane & 15);
                bfr[ni] = *(const i32x4*)&sCO[r * BK + poff];
            }
#pragma unroll
            for (int mi = 0; mi < 4; ++mi)
#pragma unroll
                for (int ni = 0; ni < 4; ++ni)
                    accO[mi][ni] = __builtin_amdgcn_mfma_i32_16x16x64_i8(
                        af[mi], bfr[ni], accO[mi][ni], 0, 0, 0);
        }
        __syncthreads();
    }

    // epilogue: C/D layout col = lane&15, row = (lane>>4)*4 + reg; butterfly
    const float sB_s = 2.0f / 127.0f;
    const int mrow0 = rowBase + waveM * 64 + (lane >> 4) * 4;
    const int ncol0 = colBase + waveN * 64 + (lane & 15);
#pragma unroll
    for (int mi = 0; mi < 4; ++mi)
#pragma unroll
        for (int ni = 0; ni < 4; ++ni)
#pragma unroll
            for (int rg = 0; rg < 4; ++rg) {
                int rr = mrow0 + mi * 16 + rg;
                int cc = ncol0 + ni * 16;
                float e = (float)accE[mi][ni][rg] * (se[rr] * sB_s);
                float o = (float)accO[mi][ni][rg] * (so[rr] * sB_s);
                C[(size_t)rr * NN + cc] = e + o;
                C[(size_t)rr * NN + (NN - 1 - cc)] = e - o;
            }
}

// ---- fallback: direct O(N^2) eval (only if ws_size is too small) ----
__global__ __launch_bounds__(256) void idct_naive(const float* __restrict__ x,
                                                  float* __restrict__ out) {
    int row = blockIdx.x;
    __shared__ float sx[NN];
    for (int i = threadIdx.x; i < NN; i += 256) sx[i] = x[(size_t)row * NN + i];
    __syncthreads();
    const float s = 3.834951969714103e-4f;  // pi / 8192
    for (int k = threadIdx.x; k < NN; k += 256) {
        int twok1 = 2 * k + 1;
        float acc = sx[0];
        int p = 0;
        for (int n = 1; n < NN; ++n) {
            p += twok1; p &= 16383;
            acc += 2.0f * sx[n] * __cosf((float)p * s);
        }
        out[(size_t)row * NN + k] = acc;
    }
}

extern "C" void kernel_launch(void* const* d_in, const int* in_sizes, int n_in,
                              void* d_out, int out_size, void* d_ws, size_t ws_size,
                              hipStream_t stream) {
    const float* x = (const float*)d_in[0];
    float* out = (float*)d_out;

    const size_t eA = (size_t)NN * HH;          // 8 MB each for Ae/Ao
    const size_t eC = (size_t)HH * HH;          // 4 MB each for CE/CO
    const size_t need = 2 * eA + 2 * eC + 2 * NN * sizeof(float);

    if (ws_size >= need) {
        signed char* Ae = (signed char*)d_ws;
        signed char* Ao = Ae + eA;
        signed char* CEm = Ao + eA;
        signed char* COm = CEm + eC;
        float* se = (float*)(COm + eC);
        float* so = se + NN;

        prep_i8<<<8192, 256, 0, stream>>>(x, Ae, Ao, CEm, COm, se, so);

        dim3 grid(HH / BN, NN / BM);            // (16, 32) = 512 blocks
        idct_gemm5<<<grid, 256, 0, stream>>>(Ae, Ao, CEm, COm, se, so, out);
    } else {
        idct_naive<<<NN, 256, 0, stream>>>(x, out);
    }
}

// Round 11
// 145.904 us; speedup vs baseline: 2.0660x; 2.0660x over previous
//
#include <hip/hip_runtime.h>
#include <cstdint>

// IDCT (DCT-III) of 4096x4096 fp32 via even/odd decimation + int8 MFMA GEMMs.
//   y_k       = E_k + O_k          (k < N/2)
//   y_{N-1-k} = E_k - O_k
// R14 (resubmit; R10-round bench was a container-infra failure, no verdict):
// branch-split waves. Model (R9=109k cy/CU): LDS reads 49.2k + writes
// 16.4k -> LDS ~90% busy in K-loop; write tail ~14us uncovered. Waves now
// {E0,E1,O0,O1}: each owns 64 rows x ALL 128 cols of ONE branch -> per-wave
// af 4 + bfr 8 = 12 reads per 32 MFMA (0.375 vs 0.5 reads/MFMA): block LDS
// reads 128->96/step (-25% on hottest pipe). acc stays 128 VGPR (no R13
// spill). K-loop lane->bank map byte-identical to R9's measured-0-conflict
// pattern. Epilogue: one-pass 64KB LDS exchange (E posts cols 64-127 e-vals,
// O posts cols 0-63 o-vals), bank-XOR col^=((row>>2)&1)<<4 -> 2-way max.
// Keeps: XCD 8x8 swizzle, staging geometry, 2-barrier loop, 2 blocks/CU.

#define NN 4096
#define HH 2048   // N/2 = K-dim of the split GEMMs and half-spectrum width
#define BM 128
#define BN 128
#define BK 128    // i8 elems per K-step (128 B rows -> proven swizzle geometry)

typedef int i32x4 __attribute__((ext_vector_type(4)));
typedef int i32x2 __attribute__((ext_vector_type(2)));

// async global->LDS, 16B per lane (HW: LDS dest = wave-uniform base + lane*16)
__device__ __forceinline__ void async_copy16(void* lds_base, const void* gptr) {
    __builtin_amdgcn_global_load_lds(
        (const __attribute__((address_space(1))) unsigned int*)gptr,
        (__attribute__((address_space(3))) unsigned int*)lds_base,
        16, 0, 0);
}

__device__ __forceinline__ int pack4(int q0, int q1, int q2, int q3) {
    return (q0 & 255) | ((q1 & 255) << 8) | ((q2 & 255) << 16) | ((q3 & 255) << 24);
}

// ---- prep ---- (unchanged; verified)
__global__ __launch_bounds__(256) void prep_i8(const float* __restrict__ x,
                                               signed char* __restrict__ Ae,
                                               signed char* __restrict__ Ao,
                                               signed char* __restrict__ CEm,
                                               signed char* __restrict__ COm,
                                               float* __restrict__ se,
                                               float* __restrict__ so) {
    const int b = blockIdx.x;
    const int t = threadIdx.x;
    const float s = 3.834951969714103e-4f;   // pi / 8192

    if (b < 4096) {
        __shared__ float wmaxe[4], wmaxo[4];
        const float* xr = x + (size_t)b * NN;
        float v[16];                          // elements n = t*16 .. t*16+15
#pragma unroll
        for (int j = 0; j < 4; ++j) {
            float4 f = ((const float4*)xr)[t * 4 + j];
            v[j * 4 + 0] = f.x; v[j * 4 + 1] = f.y;
            v[j * 4 + 2] = f.z; v[j * 4 + 3] = f.w;
        }
        float emax = 1e-30f, omax = 1e-30f;
#pragma unroll
        for (int i = 0; i < 8; ++i) {
            emax = fmaxf(emax, __builtin_fabsf(v[2 * i]));
            omax = fmaxf(omax, __builtin_fabsf(v[2 * i + 1]));
        }
        // 64-lane butterfly reduce (no barrier)
#pragma unroll
        for (int m = 1; m < 64; m <<= 1) {
            emax = fmaxf(emax, __shfl_xor(emax, m));
            omax = fmaxf(omax, __shfl_xor(omax, m));
        }
        const int wv = t >> 6;
        if ((t & 63) == 0) { wmaxe[wv] = emax; wmaxo[wv] = omax; }
        __syncthreads();
        const float rmax_e = fmaxf(fmaxf(wmaxe[0], wmaxe[1]), fmaxf(wmaxe[2], wmaxe[3]));
        const float rmax_o = fmaxf(fmaxf(wmaxo[0], wmaxo[1]), fmaxf(wmaxo[2], wmaxo[3]));
        const float inv_e = 127.0f / rmax_e, inv_o = 127.0f / rmax_o;
        int qe[8], qo[8];
#pragma unroll
        for (int i = 0; i < 8; ++i) {
            qe[i] = (int)rintf(v[2 * i] * inv_e);
            qo[i] = (int)rintf(v[2 * i + 1] * inv_o);
        }
        i32x2 oe, oo;
        oe[0] = pack4(qe[0], qe[1], qe[2], qe[3]);
        oe[1] = pack4(qe[4], qe[5], qe[6], qe[7]);
        oo[0] = pack4(qo[0], qo[1], qo[2], qo[3]);
        oo[1] = pack4(qo[4], qo[5], qo[6], qo[7]);
        ((i32x2*)(Ae + (size_t)b * HH))[t] = oe;   // m = t*8 .. t*8+7
        ((i32x2*)(Ao + (size_t)b * HH))[t] = oo;
        if (t == 0) {
            se[b] = rmax_e * (1.0f / 127.0f);
            so[b] = rmax_o * (1.0f / 127.0f);
        }
    } else if (b < 6144) {
        const int k = b - 4096;
        const int twok1 = 2 * k + 1;
        int q[8];
#pragma unroll
        for (int i = 0; i < 8; ++i) {
            int m = t * 8 + i;
            int p = (2 * m * twok1) & 16383;            // angle = p * pi/8192
            float w = (m == 0) ? 1.0f : 2.0f;
            q[i] = (int)rintf(w * __cosf((float)p * s) * 63.5f);  // scale 2/127
        }
        i32x2 o;
        o[0] = pack4(q[0], q[1], q[2], q[3]);
        o[1] = pack4(q[4], q[5], q[6], q[7]);
        ((i32x2*)(CEm + (size_t)k * HH))[t] = o;
    } else {
        const int k = b - 6144;
        const int twok1 = 2 * k + 1;
        int q[8];
#pragma unroll
        for (int i = 0; i < 8; ++i) {
            int m = t * 8 + i;
            int p = ((2 * m + 1) * twok1) & 16383;
            q[i] = (int)rintf(__cosf((float)p * s) * 127.0f);     // 2*cos, scale 2/127
        }
        i32x2 o;
        o[0] = pack4(q[0], q[1], q[2], q[3]);
        o[1] = pack4(q[4], q[5], q[6], q[7]);
        ((i32x2*)(COm + (size_t)k * HH))[t] = o;
    }
}

// ---- fused split GEMM, branch-split waves ----
// 128x128 tile, BK=128. Wave wB = wave>>1 (0=E,1=O), wM = wave&1 (row half).
// Each wave: 64 rows x 128 cols of its branch = 4x8 grid of 16x16x64 MFMA,
// acc 128 VGPR. Per kk: af[4] + bfr[8] = 12 ds_read_b128, 32 MFMA.
__global__ __launch_bounds__(256, 2) void idct_gemm6(const signed char* __restrict__ Ae,
                                                     const signed char* __restrict__ Ao,
                                                     const signed char* __restrict__ CEm,
                                                     const signed char* __restrict__ COm,
                                                     const float* __restrict__ se,
                                                     const float* __restrict__ so,
                                                     float* __restrict__ C) {
    __shared__ __align__(16) signed char lds[65536];     // 64 KB, 2 blocks/CU
    signed char* sAe = lds;                              // 16 KB
    signed char* sAo = lds + 16384;                      // 16 KB
    signed char* sCE = lds + 32768;                      // 16 KB
    signed char* sCO = lds + 49152;                      // 16 KB

    const int tid  = threadIdx.x;
    const int wave = tid >> 6;
    const int lane = tid & 63;
    const int wB = wave >> 1;           // 0 = E branch, 1 = O branch
    const int wM = wave & 1;            // row half: rows wM*64 .. +64

    // XCD-aware swizzle (R9): XCD q owns an 8x8 tile of the 16x32 grid.
    const int lid = blockIdx.y * gridDim.x + blockIdx.x;   // 0..511
    const int q8  = lid & 7;
    const int jj  = lid >> 3;                              // 0..63
    const int bx  = (q8 & 1) * 8 + (jj & 7);               // 0..15
    const int by  = (q8 >> 1) * 8 + (jj >> 3);             // 0..31

    const int rowBase = by * BM;        // output rows
    const int colBase = bx * BN;        // half-spectrum cols k in [0,2048)

    i32x4 acc[4][8] = {};               // 4 row-tiles x 8 col-tiles, one branch

    // staging: chunk = 1 KB = 8 rows x 8 granules(16B); 16 chunks per matrix
    const int srow  = lane >> 3;              // row within chunk (== r&7)
    const int sgran = lane & 7;               // physical granule this lane fills
    const int ggcol = (sgran ^ srow) * 16;    // swizzle baked into global col (bytes)
    const int rmod  = lane & 7;
    const int quad  = lane >> 4;

    const signed char* SA = wB ? sAo : sAe;   // this wave's LDS A source
    const signed char* SB = wB ? sCO : sCE;   // this wave's LDS B source

    for (int k0 = 0; k0 < HH; k0 += BK) {
#pragma unroll
        for (int j = 0; j < 4; ++j) {
            int ck = wave * 4 + j;                // chunk 0..15 (8 rows each)
            int r  = ck * 8 + srow;               // 0..127
            size_t aoff = (size_t)(rowBase + r) * HH + k0 + ggcol;
            size_t boff = (size_t)(colBase + r) * HH + k0 + ggcol;
            async_copy16(&sAe[ck * 1024], Ae + aoff);
            async_copy16(&sAo[ck * 1024], Ao + aoff);
            async_copy16(&sCE[ck * 1024], CEm + boff);
            async_copy16(&sCO[ck * 1024], COm + boff);
        }
        __syncthreads();

#pragma unroll
        for (int kk = 0; kk < 2; ++kk) {
            // logical granule g = kk*4 + quad; physical p = g ^ (r&7)
            // (rows are bank-neutral at 128B stride; lane->bank map == R9)
            const int poff = ((kk * 4 + quad) ^ rmod) * 16;   // bytes
            i32x4 af[4];
#pragma unroll
            for (int mi = 0; mi < 4; ++mi) {
                int r = wM * 64 + mi * 16 + (lane & 15);
                af[mi] = *(const i32x4*)&SA[r * BK + poff];
            }
#pragma unroll
            for (int ni = 0; ni < 8; ++ni) {
                int r = ni * 16 + (lane & 15);
                i32x4 bfr = *(const i32x4*)&SB[r * BK + poff];
#pragma unroll
                for (int mi = 0; mi < 4; ++mi)
                    acc[mi][ni] = __builtin_amdgcn_mfma_i32_16x16x64_i8(
                        af[mi], bfr, acc[mi][ni], 0, 0, 0);
            }
        }
        __syncthreads();
    }

    // ---- epilogue: one-pass LDS exchange + butterfly ----
    // C/D layout: col = lane&15, row = (lane>>4)*4 + reg.
    // E-wave posts e-vals for cols 64..127 (ni 4-7); O-wave posts o-vals for
    // cols 0..63 (ni 0-3). After barrier: E butterflies cols 0..63 (own e +
    // LDS o), O butterflies cols 64..127 (own o + LDS e).
    // xch[r][c] at float-index r*128 + (c ^ ((r>>2 & 1)<<4)): per-instruction
    // lanes = 16 cols x rows {b,b+4,b+8,b+12} -> XOR splits row-pairs across
    // bank halves -> 2-way max (free).
    const float sB_s = 2.0f / 127.0f;
    const float* scale = wB ? so : se;
    float* xch = (float*)lds;

    __syncthreads();   // all K-loop LDS reads done before overwrite
#pragma unroll
    for (int mi = 0; mi < 4; ++mi)
#pragma unroll
        for (int nj = 0; nj < 4; ++nj)
#pragma unroll
            for (int rg = 0; rg < 4; ++rg) {
                const int ni = wB ? nj : nj + 4;      // O posts 0-63, E posts 64-127
                int rl = wM * 64 + mi * 16 + (lane >> 4) * 4 + rg;
                int cl = ni * 16 + (lane & 15);
                float v = (float)acc[mi][ni][rg] * (scale[rowBase + rl] * sB_s);
                xch[rl * 128 + (cl ^ (((rl >> 2) & 1) << 4))] = v;
            }
    __syncthreads();
#pragma unroll
    for (int mi = 0; mi < 4; ++mi)
#pragma unroll
        for (int nj = 0; nj < 4; ++nj)
#pragma unroll
            for (int rg = 0; rg < 4; ++rg) {
                const int ni = wB ? nj + 4 : nj;      // E stores 0-63, O stores 64-127
                int rl = wM * 64 + mi * 16 + (lane >> 4) * 4 + rg;
                int cl = ni * 16 + (lane & 15);
                float own = (float)acc[mi][ni][rg] * (scale[rowBase + rl] * sB_s);
                float oth = xch[rl * 128 + (cl ^ (((rl >> 2) & 1) << 4))];
                float e = wB ? oth : own;
                float o = wB ? own : oth;
                int rr = rowBase + rl;
                int cc = colBase + cl;
                C[(size_t)rr * NN + cc] = e + o;
                C[(size_t)rr * NN + (NN - 1 - cc)] = e - o;
            }
}

// ---- fallback: direct O(N^2) eval (only if ws_size is too small) ----
__global__ __launch_bounds__(256) void idct_naive(const float* __restrict__ x,
                                                  float* __restrict__ out) {
    int row = blockIdx.x;
    __shared__ float sx[NN];
    for (int i = threadIdx.x; i < NN; i += 256) sx[i] = x[(size_t)row * NN + i];
    __syncthreads();
    const float s = 3.834951969714103e-4f;  // pi / 8192
    for (int k = threadIdx.x; k < NN; k += 256) {
        int twok1 = 2 * k + 1;
        float acc = sx[0];
        int p = 0;
        for (int n = 1; n < NN; ++n) {
            p += twok1; p &= 16383;
            acc += 2.0f * sx[n] * __cosf((float)p * s);
        }
        out[(size_t)row * NN + k] = acc;
    }
}

extern "C" void kernel_launch(void* const* d_in, const int* in_sizes, int n_in,
                              void* d_out, int out_size, void* d_ws, size_t ws_size,
                              hipStream_t stream) {
    const float* x = (const float*)d_in[0];
    float* out = (float*)d_out;

    const size_t eA = (size_t)NN * HH;          // 8 MB each for Ae/Ao
    const size_t eC = (size_t)HH * HH;          // 4 MB each for CE/CO
    const size_t need = 2 * eA + 2 * eC + 2 * NN * sizeof(float);

    if (ws_size >= need) {
        signed char* Ae = (signed char*)d_ws;
        signed char* Ao = Ae + eA;
        signed char* CEm = Ao + eA;
        signed char* COm = CEm + eC;
        float* se = (float*)(COm + eC);
        float* so = se + NN;

        prep_i8<<<8192, 256, 0, stream>>>(x, Ae, Ao, CEm, COm, se, so);

        dim3 grid(HH / BN, NN / BM);            // (16, 32) = 512 blocks
        idct_gemm6<<<grid, 256, 0, stream>>>(Ae, Ao, CEm, COm, se, so, out);
    } else {
        idct_naive<<<NN, 256, 0, stream>>>(x, out);
    }
}